// Round 1
// baseline (257.823 us; speedup 1.0000x reference)
//
#include <hip/hip_runtime.h>
#include <hip/hip_bf16.h>

// Problem constants: B=2, S=2048, D=1024, H=16, HD=64
#define B_  2
#define S_  2048
#define D_  1024
#define H_  16
#define HD_ 64

using bf16x8  = __attribute__((ext_vector_type(8))) __bf16;
using floatx4 = __attribute__((ext_vector_type(4))) float;
using intx4   = __attribute__((ext_vector_type(4))) int;

__device__ __forceinline__ float bf2f(unsigned short u) {
  union { unsigned int i; float f; } v; v.i = ((unsigned int)u) << 16; return v.f;
}
__device__ __forceinline__ unsigned short f2bf(float f) {
  union { float f; unsigned int i; } v; v.f = f;
  unsigned int r = v.i + 0x7fffu + ((v.i >> 16) & 1u);   // RNE
  return (unsigned short)(r >> 16);
}
// packed f32x2 -> bf16x2 (v_cvt_pk_bf16_f32 on gfx950; header fallback = same RNE)
__device__ __forceinline__ unsigned int f2bf_pk(float a, float b) {
  union { __hip_bfloat162 h2; unsigned int u; } c;
  c.h2 = __float22bfloat162_rn(make_float2(a, b));
  return c.u;   // low 16 = a, high 16 = b
}
__device__ __forceinline__ floatx4 mfma16(bf16x8 a, bf16x8 b, floatx4 c) {
  return __builtin_amdgcn_mfma_f32_16x16x32_bf16(a, b, c, 0, 0, 0);
}
// async global->LDS, 16B/lane; LDS dest = wave-uniform base + lane*16
__device__ __forceinline__ void gld16(const unsigned short* g, unsigned short* l) {
  __builtin_amdgcn_global_load_lds(
      (const __attribute__((address_space(1))) unsigned int*)g,
      (__attribute__((address_space(3))) unsigned int*)l, 16, 0, 0);
}
// swizzles: ushort offset of 8-ushort group within a row
#define SW8(row, g) ((((g) ^ ((row) & 7)) * 8))          // 64-ushort rows
#define SW4(row, g) ((((g) ^ (((row) >> 1) & 3)) * 8))   // 32-ushort rows

// ---------------------------------------------------------------------------
// prep: one dispatch doing all pre-passes (launch-overhead fusion).
// blocks [0,2048): cvt x | [2048,3072): cvt w_in[0:2048] | [3072,3584): cvt
// w_out | [3584,5632): mask->bitpack | [5632,6656): V transpose to [B][H][HD][S]
// ---------------------------------------------------------------------------
__global__ __launch_bounds__(256) void prep_kernel(
    const float* __restrict__ x, const float* __restrict__ w_in,
    const float* __restrict__ w_out, const float* __restrict__ V,
    const float* __restrict__ Mm,
    unsigned short* __restrict__ xb, unsigned short* __restrict__ wb,
    unsigned short* __restrict__ wob, unsigned short* __restrict__ vt,
    unsigned long long* __restrict__ mpk)
{
  __shared__ unsigned short tile[64 * 72];
  const int bid = blockIdx.x, tid = threadIdx.x;

  if (bid < 3584) {                       // bulk fp32->bf16 converts
    const float* src; unsigned short* dst; int base;
    if (bid < 2048)      { src = x;     dst = xb;  base = bid; }
    else if (bid < 3072) { src = w_in;  dst = wb;  base = bid - 2048; }
    else                 { src = w_out; dst = wob; base = bid - 3072; }
    const int i = (base * 256 + tid) * 8;
    float4 a = *(const float4*)(src + i);
    float4 b = *(const float4*)(src + i + 4);
    union { unsigned int w[4]; intx4 v; } o;
    o.w[0] = f2bf_pk(a.x, a.y); o.w[1] = f2bf_pk(a.z, a.w);
    o.w[2] = f2bf_pk(b.x, b.y); o.w[3] = f2bf_pk(b.z, b.w);
    *(intx4*)(dst + i) = o.v;
  } else if (bid < 5632) {                // mask bit-pack, 64 words/block
    const int wave = tid >> 6, lane = tid & 63;
    const int w0 = (bid - 3584) * 64 + wave * 16;
#pragma unroll 4
    for (int j = 0; j < 16; ++j) {
      float v = Mm[(size_t)(w0 + j) * 64 + lane];
      unsigned long long bl = __ballot(v != 0.0f);
      if (lane == 0) mpk[w0 + j] = bl;
    }
  } else {                                 // V transpose (b,h,64-token tile)
    const int idx = bid - 5632;
    const int t0 = (idx & 31) * 64, h = (idx >> 5) & 15, b = idx >> 9;
    const int sr = tid >> 3, sc = (tid & 7) * 8;
    const float* src = V + ((size_t)((b * S_ + t0) * H_ + h)) * HD_;
#pragma unroll
    for (int half = 0; half < 2; ++half) {
      const int r = sr + half * 32;
      float4 v0 = *(const float4*)&src[(size_t)r * (H_ * HD_) + sc];
      float4 v1 = *(const float4*)&src[(size_t)r * (H_ * HD_) + sc + 4];
      union { unsigned int w[4]; intx4 v; } p;
      p.w[0] = f2bf_pk(v0.x, v0.y); p.w[1] = f2bf_pk(v0.z, v0.w);
      p.w[2] = f2bf_pk(v1.x, v1.y); p.w[3] = f2bf_pk(v1.z, v1.w);
      *(intx4*)&tile[r * 72 + sc] = p.v;
    }
    __syncthreads();
    unsigned short* dst = vt + ((size_t)((b * H_ + h) * HD_)) * S_ + t0;
    union { unsigned short u[8]; intx4 v; } pack;
#pragma unroll
    for (int j = 0; j < 8; ++j) pack.u[j] = tile[(sc + j) * 72 + sr];
    *(intx4*)&dst[(size_t)sr * S_ + sc] = pack.v;
#pragma unroll
    for (int j = 0; j < 8; ++j) pack.u[j] = tile[(sc + j) * 72 + sr + 32];
    *(intx4*)&dst[(size_t)(sr + 32) * S_ + sc] = pack.v;
  }
}

// ---------------------------------------------------------------------------
// bf16 MFMA GEMM (m97-style): C = A @ Bm^T + bias. 128x128, BK=32,
// global_load_lds + XOR-swizzled LDS. qscale: cols<1024 *= 0.125.
// ---------------------------------------------------------------------------
__global__ __launch_bounds__(256) void gemm_abt(
    const unsigned short* __restrict__ A,
    const unsigned short* __restrict__ Bm,
    const float* __restrict__ bias,
    unsigned short* __restrict__ Cb, float* __restrict__ Cf,
    int M, int N, int K, int qscale)
{
  __shared__ unsigned short As[128 * 32];
  __shared__ unsigned short Bs[128 * 32];

  const int tid  = threadIdx.x;
  const int wave = tid >> 6, lane = tid & 63;
  const int quad = lane >> 4, l15 = lane & 15;
  const int wr = wave >> 1, wc = wave & 1;
  const int bm = blockIdx.y * 128, bn = blockIdx.x * 128;
  const int srow = tid >> 2, gs = tid & 3;

  floatx4 acc[4][4];
#pragma unroll
  for (int mt = 0; mt < 4; ++mt)
#pragma unroll
    for (int nt = 0; nt < 4; ++nt)
      acc[mt][nt] = (floatx4){0.f, 0.f, 0.f, 0.f};

  for (int k0 = 0; k0 < K; k0 += 32) {
    __syncthreads();
#pragma unroll
    for (int r = 0; r < 2; ++r) {
      const int row = srow + r * 64;
      gld16(&A[(size_t)(bm + row) * K + k0 + SW4(row, gs)],
            &As[wave * 512 + r * 2048]);
      gld16(&Bm[(size_t)(bn + row) * K + k0 + SW4(row, gs)],
            &Bs[wave * 512 + r * 2048]);
    }
    __syncthreads();

    bf16x8 af[4], bf[4];
#pragma unroll
    for (int mt = 0; mt < 4; ++mt) {
      const int row = wr * 64 + mt * 16 + l15;
      af[mt] = *(const bf16x8*)&As[row * 32 + SW4(row, quad)];
    }
#pragma unroll
    for (int nt = 0; nt < 4; ++nt) {
      const int row = wc * 64 + nt * 16 + l15;
      bf[nt] = *(const bf16x8*)&Bs[row * 32 + SW4(row, quad)];
    }
#pragma unroll
    for (int mt = 0; mt < 4; ++mt)
#pragma unroll
      for (int nt = 0; nt < 4; ++nt)
        acc[mt][nt] = mfma16(af[mt], bf[nt], acc[mt][nt]);
  }

#pragma unroll
  for (int nt = 0; nt < 4; ++nt) {
    const int col = bn + wc * 64 + nt * 16 + l15;
    const float bi = bias[col];
    const float sc = (qscale && col < 1024) ? 0.125f : 1.0f;
#pragma unroll
    for (int mt = 0; mt < 4; ++mt) {
      const int row0 = bm + wr * 64 + mt * 16 + quad * 4;
#pragma unroll
      for (int reg = 0; reg < 4; ++reg) {
        const float v = (acc[mt][nt][reg] + bi) * sc;
        if (Cf) Cf[(size_t)(row0 + reg) * N + col] = v;
        else    Cb[(size_t)(row0 + reg) * N + col] = f2bf(v);
      }
    }
  }
}

// ---------------------------------------------------------------------------
// Fused masked-renorm attention: out = sum(e*M*V)/sum(e*M).
// Block = (b,h,128 q-rows), 4 waves, wave w owns rows [w*32,w*32+32).
// Double-buffered K/V/mask staging (prefetch t+1 before compute t) ->
// one barrier per tile. P round-trip is wave-private: ordered by
// s_waitcnt lgkmcnt(0) + compiler fence, no block barrier. Ps aliases the
// dead Qs region (q frags live in registers after the pre-loop).
// ---------------------------------------------------------------------------
__global__ __launch_bounds__(256) void attn_kernel(
    const unsigned short* __restrict__ QK,      // [B*S][2048]
    const unsigned short* __restrict__ Vt,      // [B][H][HD][S]
    const unsigned long long* __restrict__ Mpk, // [B*S][S/64]
    unsigned short* __restrict__ ctx)           // [B*S][D]
{
  __shared__ unsigned short PQ[128 * 72];       // Qs(stride 64) ∪ Ps(stride 72)
  __shared__ unsigned short Ks[2][64 * 64];
  __shared__ unsigned short Vs[2][64 * 64];
  __shared__ unsigned long long Ms64[2][128];

  const int tid  = threadIdx.x;
  const int wave = tid >> 6, lane = tid & 63;
  const int quad = lane >> 4, l15 = lane & 15;
  const int b = blockIdx.z, h = blockIdx.y, qb = blockIdx.x * 128;
  const int gs = tid & 7;

  const unsigned short* Qbase = QK + (size_t)(b * S_ + qb) * 2048 + h * HD_;
  const unsigned short* Kbase = QK + (size_t)(b * S_) * 2048 + D_ + h * HD_;
  const unsigned short* Vbase = Vt + (size_t)((b * H_ + h) * HD_) * S_;
  const unsigned long long* Mbase = Mpk + (size_t)(b * S_ + qb) * (S_ / 64);

  // stage Q (128x64, stride 64) + tile 0 K/V + mask words
#pragma unroll
  for (int r = 0; r < 4; ++r) {
    const int row = (tid >> 3) + r * 32;
    gld16(Qbase + (size_t)row * 2048 + SW8(row, gs), &PQ[wave * 512 + r * 2048]);
  }
#pragma unroll
  for (int r = 0; r < 2; ++r) {
    const int row = (tid >> 3) + r * 32;
    gld16(Kbase + (size_t)row * 2048 + SW8(row, gs), &Ks[0][wave * 512 + r * 2048]);
    gld16(Vbase + (size_t)row * S_ + SW8(row, gs),   &Vs[0][wave * 512 + r * 2048]);
  }
  if (tid < 128) Ms64[0][tid] = Mbase[(size_t)tid * (S_ / 64)];
  asm volatile("s_waitcnt vmcnt(0)" ::: "memory");
  __syncthreads();

  // loop-invariant Q fragments (rows wave*32..+31, stride-64 layout)
  bf16x8 qf[2][2];
#pragma unroll
  for (int mt = 0; mt < 2; ++mt)
#pragma unroll
    for (int c = 0; c < 2; ++c) {
      const int row = wave * 32 + mt * 16 + l15;
      qf[mt][c] = *(const bf16x8*)&PQ[row * 64 + SW8(row, c * 4 + quad)];
    }
  asm volatile("s_waitcnt lgkmcnt(0)" ::: "memory");  // q reads before Ps writes

  floatx4 accO[2][4];
  float Pp[2][4];
#pragma unroll
  for (int mt = 0; mt < 2; ++mt)
#pragma unroll
    for (int nt = 0; nt < 4; ++nt) {
      accO[mt][nt] = (floatx4){0.f, 0.f, 0.f, 0.f};
      Pp[mt][nt] = 0.f;
    }

  for (int i = 0; i < 32; ++i) {
    const int cur = i & 1, nxt = cur ^ 1;
    asm volatile("s_waitcnt vmcnt(0)" ::: "memory");  // buf[cur] staged
    __syncthreads();  // all waves done with buf[nxt] (tile i-1) + Qs reads (i=0)

    if (i + 1 < 32) {  // prefetch tile i+1 (drained at next iteration's top)
      const int t1 = (i + 1) * 64;
#pragma unroll
      for (int r = 0; r < 2; ++r) {
        const int row = (tid >> 3) + r * 32;
        gld16(Kbase + (size_t)(t1 + row) * 2048 + SW8(row, gs),
              &Ks[nxt][wave * 512 + r * 2048]);
        gld16(Vbase + (size_t)row * S_ + t1 + SW8(row, gs),
              &Vs[nxt][wave * 512 + r * 2048]);
      }
      if (tid < 128)
        Ms64[nxt][tid] = Mbase[(size_t)tid * (S_ / 64) + i + 1];
    }

    // S = Q @ K^T
    floatx4 sc[2][4];
#pragma unroll
    for (int nt = 0; nt < 4; ++nt) {
      const int row = nt * 16 + l15;
      bf16x8 kf0 = *(const bf16x8*)&Ks[cur][row * 64 + SW8(row, quad)];
      bf16x8 kf1 = *(const bf16x8*)&Ks[cur][row * 64 + SW8(row, 4 + quad)];
#pragma unroll
      for (int mt = 0; mt < 2; ++mt) {
        floatx4 z = (floatx4){0.f, 0.f, 0.f, 0.f};
        z = mfma16(qf[mt][0], kf0, z);
        z = mfma16(qf[mt][1], kf1, z);
        sc[mt][nt] = z;
      }
    }

    unsigned long long mw[2][4];
#pragma unroll
    for (int mt = 0; mt < 2; ++mt)
#pragma unroll
      for (int reg = 0; reg < 4; ++reg)
        mw[mt][reg] = Ms64[cur][wave * 32 + mt * 16 + quad * 4 + reg];

    // exp, mask, P-sum, packed bf16 stage into Ps (stride 72, wave-private)
#pragma unroll
    for (int mt = 0; mt < 2; ++mt)
#pragma unroll
      for (int nt = 0; nt < 4; ++nt)
#pragma unroll
        for (int rp = 0; rp < 2; ++rp) {
          const int r0 = rp * 2, r1 = rp * 2 + 1;
          float e0 = __expf(sc[mt][nt][r0]);
          float e1 = __expf(sc[mt][nt][r1]);
          unsigned int w0 = (nt < 2) ? (unsigned int)mw[mt][r0]
                                     : (unsigned int)(mw[mt][r0] >> 32);
          unsigned int w1 = (nt < 2) ? (unsigned int)mw[mt][r1]
                                     : (unsigned int)(mw[mt][r1] >> 32);
          const int sh = (nt & 1) * 16 + l15;
          float p0 = ((w0 >> sh) & 1u) ? e0 : 0.0f;
          float p1 = ((w1 >> sh) & 1u) ? e1 : 0.0f;
          Pp[mt][r0] += p0;
          Pp[mt][r1] += p1;
          unsigned int u = f2bf_pk(p0, p1);
          const int rowA = wave * 32 + mt * 16 + quad * 4 + r0;
          const int cg = nt * 2 + (l15 >> 3), co = l15 & 7;
          PQ[rowA * 72 + SW8(rowA, cg) + co] = (unsigned short)u;
          PQ[(rowA + 1) * 72 + SW8(rowA + 1, cg) + co] = (unsigned short)(u >> 16);
        }

    // wave-private ordering of Ps stores vs frag loads (no block barrier)
    asm volatile("s_waitcnt lgkmcnt(0)" ::: "memory");

    // O += P @ V^T
    bf16x8 pf0[2], pf1[2];
#pragma unroll
    for (int mt = 0; mt < 2; ++mt) {
      const int row = wave * 32 + mt * 16 + l15;
      pf0[mt] = *(const bf16x8*)&PQ[row * 72 + SW8(row, quad)];
      pf1[mt] = *(const bf16x8*)&PQ[row * 72 + SW8(row, 4 + quad)];
    }
#pragma unroll
    for (int nt = 0; nt < 4; ++nt) {
      const int row = nt * 16 + l15;
      bf16x8 vf0 = *(const bf16x8*)&Vs[cur][row * 64 + SW8(row, quad)];
      bf16x8 vf1 = *(const bf16x8*)&Vs[cur][row * 64 + SW8(row, 4 + quad)];
#pragma unroll
      for (int mt = 0; mt < 2; ++mt) {
        accO[mt][nt] = mfma16(pf0[mt], vf0, accO[mt][nt]);
        accO[mt][nt] = mfma16(pf1[mt], vf1, accO[mt][nt]);
      }
    }
  }

  // reduce P-sums over the 16 lanes of each quad
#pragma unroll
  for (int off = 1; off <= 8; off <<= 1)
#pragma unroll
    for (int mt = 0; mt < 2; ++mt)
#pragma unroll
      for (int reg = 0; reg < 4; ++reg)
        Pp[mt][reg] += __shfl_xor(Pp[mt][reg], off);

#pragma unroll
  for (int mt = 0; mt < 2; ++mt)
#pragma unroll
    for (int reg = 0; reg < 4; ++reg)
      Pp[mt][reg] = 1.0f / (Pp[mt][reg] + 1e-30f);

#pragma unroll
  for (int mt = 0; mt < 2; ++mt)
#pragma unroll
    for (int nt = 0; nt < 4; ++nt)
#pragma unroll
      for (int reg = 0; reg < 4; ++reg) {
        const int row = wave * 32 + mt * 16 + quad * 4 + reg;
        ctx[(size_t)(b * S_ + qb + row) * D_ + h * HD_ + nt * 16 + l15] =
            f2bf(accO[mt][nt][reg] * Pp[mt][reg]);
      }
}

// ---------------------------------------------------------------------------
extern "C" void kernel_launch(void* const* d_in, const int* in_sizes, int n_in,
                              void* d_out, int out_size, void* d_ws, size_t ws_size,
                              hipStream_t stream) {
  const float* x     = (const float*)d_in[0];
  const float* V     = (const float*)d_in[1];
  const float* Mm    = (const float*)d_in[2];
  const float* w_in  = (const float*)d_in[3];
  const float* b_in  = (const float*)d_in[4];
  const float* w_out = (const float*)d_in[5];
  const float* b_out = (const float*)d_in[6];
  float* out = (float*)d_out;                  // fp32 (verified R5)

  // workspace layout (ushort units)
  unsigned short* qk  = (unsigned short*)d_ws;          // 8M   [4096][2048]
  unsigned short* vt  = qk  + (size_t)8 * 1024 * 1024;  // 4M   [B][H][HD][S]
  unsigned short* ctx = vt  + (size_t)4 * 1024 * 1024;  // 4M   [4096][1024]
  unsigned short* xb  = ctx + (size_t)4 * 1024 * 1024;  // 4M   bf16(x)
  unsigned short* wb  = xb  + (size_t)4 * 1024 * 1024;  // 2M   bf16(w_in[0:2048])
  unsigned short* wob = wb  + (size_t)2 * 1024 * 1024;  // 1M   bf16(out_w)
  unsigned long long* mpk = (unsigned long long*)(wob + (size_t)1024 * 1024);

  // 0) fused prep: converts + mask pack + V transpose (one dispatch)
  prep_kernel<<<6656, 256, 0, stream>>>(x, w_in, w_out, V, Mm,
                                        xb, wb, wob, vt, mpk);

  // 1) QK = x @ in_proj_w[0:2048]^T + b_in; Q cols pre-scaled by 0.125
  gemm_abt<<<dim3(2048 / 128, (B_ * S_) / 128), 256, 0, stream>>>(
      xb, wb, b_in, qk, nullptr, B_ * S_, 2048, D_, 1);

  // 2) fused masked-renorm attention -> ctx (bf16)
  attn_kernel<<<dim3(S_ / 128, H_, B_), 256, 0, stream>>>(qk, vt, mpk, ctx);

  // 3) out = ctx @ out_w^T + out_b  (fp32 store to d_out)
  gemm_abt<<<dim3(D_ / 128, (B_ * S_) / 128), 256, 0, stream>>>(
      ctx, wob, b_out, nullptr, out, B_ * S_, D_, D_, 0);
}

// Round 2
// 250.713 us; speedup vs baseline: 1.0284x; 1.0284x over previous
//
#include <hip/hip_runtime.h>
#include <hip/hip_bf16.h>

// Problem constants: B=2, S=2048, D=1024, H=16, HD=64
#define B_  2
#define S_  2048
#define D_  1024
#define H_  16
#define HD_ 64

using bf16x8  = __attribute__((ext_vector_type(8))) __bf16;
using floatx4 = __attribute__((ext_vector_type(4))) float;
using intx4   = __attribute__((ext_vector_type(4))) int;

__device__ __forceinline__ unsigned short f2bf(float f) {
  union { float f; unsigned int i; } v; v.f = f;
  unsigned int r = v.i + 0x7fffu + ((v.i >> 16) & 1u);   // RNE
  return (unsigned short)(r >> 16);
}
// packed f32x2 -> bf16x2 (v_cvt_pk_bf16_f32 on gfx950; header fallback = same RNE)
__device__ __forceinline__ unsigned int f2bf_pk(float a, float b) {
  union { __hip_bfloat162 h2; unsigned int u; } c;
  c.h2 = __float22bfloat162_rn(make_float2(a, b));
  return c.u;   // low 16 = a, high 16 = b
}
__device__ __forceinline__ floatx4 mfma16(bf16x8 a, bf16x8 b, floatx4 c) {
  return __builtin_amdgcn_mfma_f32_16x16x32_bf16(a, b, c, 0, 0, 0);
}
// async global->LDS, 16B/lane; LDS dest = wave-uniform base + lane*16
__device__ __forceinline__ void gld16(const unsigned short* g, unsigned short* l) {
  __builtin_amdgcn_global_load_lds(
      (const __attribute__((address_space(1))) unsigned int*)g,
      (__attribute__((address_space(3))) unsigned int*)l, 16, 0, 0);
}
// swizzles: ushort offset of 8-ushort group within a row
#define SW8(row, g) ((((g) ^ ((row) & 7)) * 8))          // 64-ushort rows
#define SW4(row, g) ((((g) ^ (((row) >> 1) & 3)) * 8))   // 32-ushort rows
// K-row permutation: LDS row r holds token TAU(r); bits (b5,b4,b3,b2,b1,b0) ->
// (b5,b3,b2,b4,b1,b0). Makes swapped-QK^T score layout == PV A-frag layout.
#define TAU(r) (((r) & 0x23) | (((r) & 0x08) << 1) | (((r) & 0x04) << 1) | (((r) & 0x10) >> 2))

// ---------------------------------------------------------------------------
// prep: one dispatch doing all pre-passes (launch-overhead fusion).
// blocks [0,2048): cvt x | [2048,3072): cvt w_in[0:2048] | [3072,3584): cvt
// w_out | [3584,5632): mask->bitpack | [5632,6656): V transpose to [B][H][HD][S]
// ---------------------------------------------------------------------------
__global__ __launch_bounds__(256) void prep_kernel(
    const float* __restrict__ x, const float* __restrict__ w_in,
    const float* __restrict__ w_out, const float* __restrict__ V,
    const float* __restrict__ Mm,
    unsigned short* __restrict__ xb, unsigned short* __restrict__ wb,
    unsigned short* __restrict__ wob, unsigned short* __restrict__ vt,
    unsigned long long* __restrict__ mpk)
{
  __shared__ unsigned short tile[64 * 72];
  const int bid = blockIdx.x, tid = threadIdx.x;

  if (bid < 3584) {                       // bulk fp32->bf16 converts
    const float* src; unsigned short* dst; int base;
    if (bid < 2048)      { src = x;     dst = xb;  base = bid; }
    else if (bid < 3072) { src = w_in;  dst = wb;  base = bid - 2048; }
    else                 { src = w_out; dst = wob; base = bid - 3072; }
    const int i = (base * 256 + tid) * 8;
    float4 a = *(const float4*)(src + i);
    float4 b = *(const float4*)(src + i + 4);
    union { unsigned int w[4]; intx4 v; } o;
    o.w[0] = f2bf_pk(a.x, a.y); o.w[1] = f2bf_pk(a.z, a.w);
    o.w[2] = f2bf_pk(b.x, b.y); o.w[3] = f2bf_pk(b.z, b.w);
    *(intx4*)(dst + i) = o.v;
  } else if (bid < 5632) {                // mask bit-pack, 64 words/block
    const int wave = tid >> 6, lane = tid & 63;
    const int w0 = (bid - 3584) * 64 + wave * 16;
#pragma unroll 4
    for (int j = 0; j < 16; ++j) {
      float v = Mm[(size_t)(w0 + j) * 64 + lane];
      unsigned long long bl = __ballot(v != 0.0f);
      if (lane == 0) mpk[w0 + j] = bl;
    }
  } else {                                 // V transpose (b,h,64-token tile)
    const int idx = bid - 5632;
    const int t0 = (idx & 31) * 64, h = (idx >> 5) & 15, b = idx >> 9;
    const int sr = tid >> 3, sc = (tid & 7) * 8;
    const float* src = V + ((size_t)((b * S_ + t0) * H_ + h)) * HD_;
#pragma unroll
    for (int half = 0; half < 2; ++half) {
      const int r = sr + half * 32;
      float4 v0 = *(const float4*)&src[(size_t)r * (H_ * HD_) + sc];
      float4 v1 = *(const float4*)&src[(size_t)r * (H_ * HD_) + sc + 4];
      union { unsigned int w[4]; intx4 v; } p;
      p.w[0] = f2bf_pk(v0.x, v0.y); p.w[1] = f2bf_pk(v0.z, v0.w);
      p.w[2] = f2bf_pk(v1.x, v1.y); p.w[3] = f2bf_pk(v1.z, v1.w);
      *(intx4*)&tile[r * 72 + sc] = p.v;
    }
    __syncthreads();
    unsigned short* dst = vt + ((size_t)((b * H_ + h) * HD_)) * S_ + t0;
    union { unsigned short u[8]; intx4 v; } pack;
#pragma unroll
    for (int j = 0; j < 8; ++j) pack.u[j] = tile[(sc + j) * 72 + sr];
    *(intx4*)&dst[(size_t)sr * S_ + sc] = pack.v;
#pragma unroll
    for (int j = 0; j < 8; ++j) pack.u[j] = tile[(sc + j) * 72 + sr + 32];
    *(intx4*)&dst[(size_t)(sr + 32) * S_ + sc] = pack.v;
  }
}

// ---------------------------------------------------------------------------
// bf16 MFMA GEMM (m97-style): C = A @ Bm^T + bias. 128x128, BK=32,
// global_load_lds + XOR-swizzled LDS. qscale: cols<1024 *= 0.125.
// ---------------------------------------------------------------------------
__global__ __launch_bounds__(256) void gemm_abt(
    const unsigned short* __restrict__ A,
    const unsigned short* __restrict__ Bm,
    const float* __restrict__ bias,
    unsigned short* __restrict__ Cb, float* __restrict__ Cf,
    int M, int N, int K, int qscale)
{
  __shared__ unsigned short As[128 * 32];
  __shared__ unsigned short Bs[128 * 32];

  const int tid  = threadIdx.x;
  const int wave = tid >> 6, lane = tid & 63;
  const int quad = lane >> 4, l15 = lane & 15;
  const int wr = wave >> 1, wc = wave & 1;
  const int bm = blockIdx.y * 128, bn = blockIdx.x * 128;
  const int srow = tid >> 2, gs = tid & 3;

  floatx4 acc[4][4];
#pragma unroll
  for (int mt = 0; mt < 4; ++mt)
#pragma unroll
    for (int nt = 0; nt < 4; ++nt)
      acc[mt][nt] = (floatx4){0.f, 0.f, 0.f, 0.f};

  for (int k0 = 0; k0 < K; k0 += 32) {
    __syncthreads();
#pragma unroll
    for (int r = 0; r < 2; ++r) {
      const int row = srow + r * 64;
      gld16(&A[(size_t)(bm + row) * K + k0 + SW4(row, gs)],
            &As[wave * 512 + r * 2048]);
      gld16(&Bm[(size_t)(bn + row) * K + k0 + SW4(row, gs)],
            &Bs[wave * 512 + r * 2048]);
    }
    __syncthreads();

    bf16x8 af[4], bf[4];
#pragma unroll
    for (int mt = 0; mt < 4; ++mt) {
      const int row = wr * 64 + mt * 16 + l15;
      af[mt] = *(const bf16x8*)&As[row * 32 + SW4(row, quad)];
    }
#pragma unroll
    for (int nt = 0; nt < 4; ++nt) {
      const int row = wc * 64 + nt * 16 + l15;
      bf[nt] = *(const bf16x8*)&Bs[row * 32 + SW4(row, quad)];
    }
#pragma unroll
    for (int mt = 0; mt < 4; ++mt)
#pragma unroll
      for (int nt = 0; nt < 4; ++nt)
        acc[mt][nt] = mfma16(af[mt], bf[nt], acc[mt][nt]);
  }

#pragma unroll
  for (int nt = 0; nt < 4; ++nt) {
    const int col = bn + wc * 64 + nt * 16 + l15;
    const float bi = bias[col];
    const float sc = (qscale && col < 1024) ? 0.125f : 1.0f;
#pragma unroll
    for (int mt = 0; mt < 4; ++mt) {
      const int row0 = bm + wr * 64 + mt * 16 + quad * 4;
#pragma unroll
      for (int reg = 0; reg < 4; ++reg) {
        const float v = (acc[mt][nt][reg] + bi) * sc;
        if (Cf) Cf[(size_t)(row0 + reg) * N + col] = v;
        else    Cb[(size_t)(row0 + reg) * N + col] = f2bf(v);
      }
    }
  }
}

// ---------------------------------------------------------------------------
// Fused masked-renorm attention: out = sum(e*M*V)/sum(e*M).
// Block = (b,h,128 q-rows), 4 waves, wave w owns rows [w*32,w*32+32).
// R2: swapped QK^T (mfma(kf,qf) -> S^T, lane l15 = q-row) + TAU-permuted
// K staging rows so the score layout IS the PV A-frag layout -> P never
// leaves registers. No P LDS round-trip, no PQ buffer (Q staged transiently
// into the K region pre-loop), mask loads 8->2 ds_read_b64, V-frag reads
// hoisted above the softmax. LDS 53KB -> 34KB.
// ---------------------------------------------------------------------------
__global__ __launch_bounds__(256) void attn_kernel(
    const unsigned short* __restrict__ QK,      // [B*S][2048]
    const unsigned short* __restrict__ Vt,      // [B][H][HD][S]
    const unsigned long long* __restrict__ Mpk, // [B*S][S/64]
    unsigned short* __restrict__ ctx)           // [B*S][D]
{
  __shared__ unsigned short Ks[2][64 * 64];
  __shared__ unsigned short Vs[2][64 * 64];
  __shared__ unsigned long long Ms64[2][128];

  const int tid  = threadIdx.x;
  const int wave = tid >> 6, lane = tid & 63;
  const int quad = lane >> 4, l15 = lane & 15;
  const int b = blockIdx.z, h = blockIdx.y, qb = blockIdx.x * 128;
  const int gs = tid & 7;

  const unsigned short* Qbase = QK + (size_t)(b * S_ + qb) * 2048 + h * HD_;
  const unsigned short* Kbase = QK + (size_t)(b * S_) * 2048 + D_ + h * HD_;
  const unsigned short* Vbase = Vt + (size_t)((b * H_ + h) * HD_) * S_;
  const unsigned long long* Mbase = Mpk + (size_t)(b * S_ + qb) * (S_ / 64);

  // ---- stage Q (128x64, stride 64) into the K region (both buffers) ----
  unsigned short* Qs = &Ks[0][0];
#pragma unroll
  for (int r = 0; r < 4; ++r) {
    const int row = (tid >> 3) + r * 32;
    gld16(Qbase + (size_t)row * 2048 + SW8(row, gs), Qs + wave * 512 + r * 2048);
  }
  if (tid < 128) Ms64[0][tid] = Mbase[(size_t)tid * (S_ / 64)];
  asm volatile("s_waitcnt vmcnt(0)" ::: "memory");
  __syncthreads();

  // loop-invariant Q fragments (rows wave*32..+31)
  bf16x8 qf[2][2];
#pragma unroll
  for (int mt = 0; mt < 2; ++mt)
#pragma unroll
    for (int c = 0; c < 2; ++c) {
      const int row = wave * 32 + mt * 16 + l15;
      qf[mt][c] = *(const bf16x8*)&Qs[row * 64 + SW8(row, c * 4 + quad)];
    }
  __syncthreads();   // all qf reads done before K tile-0 staging overwrites

  // ---- stage tile 0 K (TAU-permuted rows) and V ----
#pragma unroll
  for (int r = 0; r < 2; ++r) {
    const int rowd = (tid >> 3) + r * 32;
    const int tokK = TAU(rowd);
    gld16(Kbase + (size_t)tokK * 2048 + SW8(rowd, gs), &Ks[0][wave * 512 + r * 2048]);
    gld16(Vbase + (size_t)rowd * S_ + SW8(rowd, gs),   &Vs[0][wave * 512 + r * 2048]);
  }

  // per-lane mask bit-tests: token t = n1*32 + quad*8 + n0*4 + reg
  unsigned int bmask[8];
#pragma unroll
  for (int j = 0; j < 8; ++j) bmask[j] = 1u << (quad * 8 + j);

  floatx4 accO[2][4];
  float Pp[2] = {0.f, 0.f};
#pragma unroll
  for (int mt = 0; mt < 2; ++mt)
#pragma unroll
    for (int nt = 0; nt < 4; ++nt)
      accO[mt][nt] = (floatx4){0.f, 0.f, 0.f, 0.f};

  for (int i = 0; i < 32; ++i) {
    const int cur = i & 1, nxt = cur ^ 1;
    asm volatile("s_waitcnt vmcnt(0)" ::: "memory");  // buf[cur] staged
    __syncthreads();  // all waves done with buf[nxt] (tile i-1)

    if (i + 1 < 32) {  // prefetch tile i+1
      const int t1 = (i + 1) * 64;
#pragma unroll
      for (int r = 0; r < 2; ++r) {
        const int rowd = (tid >> 3) + r * 32;
        const int tokK = TAU(rowd);
        gld16(Kbase + (size_t)(t1 + tokK) * 2048 + SW8(rowd, gs),
              &Ks[nxt][wave * 512 + r * 2048]);
        gld16(Vbase + (size_t)rowd * S_ + t1 + SW8(rowd, gs),
              &Vs[nxt][wave * 512 + r * 2048]);
      }
      if (tid < 128)
        Ms64[nxt][tid] = Mbase[(size_t)tid * (S_ / 64) + i + 1];
    }

    // S^T = K @ Q^T (swapped operands): lane l15 = q-row, quad/reg = token
    floatx4 sc[4][2];
    __builtin_amdgcn_s_setprio(1);
#pragma unroll
    for (int nt = 0; nt < 4; ++nt) {
      const int row = nt * 16 + l15;
      bf16x8 kf0 = *(const bf16x8*)&Ks[cur][row * 64 + SW8(row, quad)];
      bf16x8 kf1 = *(const bf16x8*)&Ks[cur][row * 64 + SW8(row, 4 + quad)];
#pragma unroll
      for (int mt = 0; mt < 2; ++mt) {
        floatx4 z = (floatx4){0.f, 0.f, 0.f, 0.f};
        z = mfma16(kf0, qf[mt][0], z);
        z = mfma16(kf1, qf[mt][1], z);
        sc[nt][mt] = z;
      }
    }
    __builtin_amdgcn_s_setprio(0);

    // mask words: one 64-bit word per q-row (lane-local q = l15)
    unsigned long long mw[2];
#pragma unroll
    for (int mt = 0; mt < 2; ++mt)
      mw[mt] = Ms64[cur][wave * 32 + mt * 16 + l15];

    // V fragments — independent of P, hoisted above the softmax
    bf16x8 vf0[4], vf1[4];
#pragma unroll
    for (int nt = 0; nt < 4; ++nt) {
      const int row = nt * 16 + l15;
      vf0[nt] = *(const bf16x8*)&Vs[cur][row * 64 + SW8(row, quad)];
      vf1[nt] = *(const bf16x8*)&Vs[cur][row * 64 + SW8(row, 4 + quad)];
    }

    // exp + mask + P-sum, pack straight into PV A-frags (in-register)
    bf16x8 pa0[2], pa1[2];
#pragma unroll
    for (int mt = 0; mt < 2; ++mt) {
      const unsigned int mlo = (unsigned int)mw[mt];
      const unsigned int mhi = (unsigned int)(mw[mt] >> 32);
      union { unsigned int w[4]; bf16x8 v; } A0, A1;
#pragma unroll
      for (int nt = 0; nt < 4; ++nt) {
        const unsigned int word = (nt < 2) ? mlo : mhi;
        float p[4];
#pragma unroll
        for (int reg = 0; reg < 4; ++reg) {
          const float e = __expf(sc[nt][mt][reg]);
          p[reg] = (word & bmask[(nt & 1) * 4 + reg]) ? e : 0.0f;
        }
        Pp[mt] += (p[0] + p[1]) + (p[2] + p[3]);
        const unsigned int d0 = f2bf_pk(p[0], p[1]);
        const unsigned int d1 = f2bf_pk(p[2], p[3]);
        if (nt == 0)      { A0.w[0] = d0; A0.w[1] = d1; }
        else if (nt == 1) { A0.w[2] = d0; A0.w[3] = d1; }
        else if (nt == 2) { A1.w[0] = d0; A1.w[1] = d1; }
        else              { A1.w[2] = d0; A1.w[3] = d1; }
      }
      pa0[mt] = A0.v; pa1[mt] = A1.v;
    }

    // O += P @ V^T (P already in A-frag layout)
    __builtin_amdgcn_s_setprio(1);
#pragma unroll
    for (int nt = 0; nt < 4; ++nt)
#pragma unroll
      for (int mt = 0; mt < 2; ++mt) {
        accO[mt][nt] = mfma16(pa0[mt], vf0[nt], accO[mt][nt]);
        accO[mt][nt] = mfma16(pa1[mt], vf1[nt], accO[mt][nt]);
      }
    __builtin_amdgcn_s_setprio(0);
  }

  // Pp currently: lane (quad,l15) holds partial row-sum for q = mt*16+l15
  // over that quad's tokens. Reduce over quads (lane^16, lane^32).
#pragma unroll
  for (int mt = 0; mt < 2; ++mt) {
    Pp[mt] += __shfl_xor(Pp[mt], 16);
    Pp[mt] += __shfl_xor(Pp[mt], 32);
    Pp[mt] = 1.0f / (Pp[mt] + 1e-30f);
  }
  // redistribute: epilogue needs inv-sum for q = mt*16 + quad*4 + reg
  float Ppe[2][4];
#pragma unroll
  for (int mt = 0; mt < 2; ++mt)
#pragma unroll
    for (int reg = 0; reg < 4; ++reg)
      Ppe[mt][reg] = __shfl(Pp[mt], (quad << 4) | (quad * 4 + reg));

#pragma unroll
  for (int mt = 0; mt < 2; ++mt)
#pragma unroll
    for (int nt = 0; nt < 4; ++nt)
#pragma unroll
      for (int reg = 0; reg < 4; ++reg) {
        const int row = wave * 32 + mt * 16 + quad * 4 + reg;
        ctx[(size_t)(b * S_ + qb + row) * D_ + h * HD_ + nt * 16 + l15] =
            f2bf(accO[mt][nt][reg] * Ppe[mt][reg]);
      }
}

// ---------------------------------------------------------------------------
extern "C" void kernel_launch(void* const* d_in, const int* in_sizes, int n_in,
                              void* d_out, int out_size, void* d_ws, size_t ws_size,
                              hipStream_t stream) {
  const float* x     = (const float*)d_in[0];
  const float* V     = (const float*)d_in[1];
  const float* Mm    = (const float*)d_in[2];
  const float* w_in  = (const float*)d_in[3];
  const float* b_in  = (const float*)d_in[4];
  const float* w_out = (const float*)d_in[5];
  const float* b_out = (const float*)d_in[6];
  float* out = (float*)d_out;                  // fp32 (verified R5)

  // workspace layout (ushort units)
  unsigned short* qk  = (unsigned short*)d_ws;          // 8M   [4096][2048]
  unsigned short* vt  = qk  + (size_t)8 * 1024 * 1024;  // 4M   [B][H][HD][S]
  unsigned short* ctx = vt  + (size_t)4 * 1024 * 1024;  // 4M   [4096][1024]
  unsigned short* xb  = ctx + (size_t)4 * 1024 * 1024;  // 4M   bf16(x)
  unsigned short* wb  = xb  + (size_t)4 * 1024 * 1024;  // 2M   bf16(w_in[0:2048])
  unsigned short* wob = wb  + (size_t)2 * 1024 * 1024;  // 1M   bf16(out_w)
  unsigned long long* mpk = (unsigned long long*)(wob + (size_t)1024 * 1024);

  // 0) fused prep: converts + mask pack + V transpose (one dispatch)
  prep_kernel<<<6656, 256, 0, stream>>>(x, w_in, w_out, V, Mm,
                                        xb, wb, wob, vt, mpk);

  // 1) QK = x @ in_proj_w[0:2048]^T + b_in; Q cols pre-scaled by 0.125
  gemm_abt<<<dim3(2048 / 128, (B_ * S_) / 128), 256, 0, stream>>>(
      xb, wb, b_in, qk, nullptr, B_ * S_, 2048, D_, 1);

  // 2) fused masked-renorm attention -> ctx (bf16)
  attn_kernel<<<dim3(S_ / 128, H_, B_), 256, 0, stream>>>(qk, vt, mpk, ctx);

  // 3) out = ctx @ out_w^T + out_b  (fp32 store to d_out)
  gemm_abt<<<dim3(D_ / 128, (B_ * S_) / 128), 256, 0, stream>>>(
      ctx, wob, b_out, nullptr, out, B_ * S_, D_, D_, 0);
}

// Round 3
// 247.585 us; speedup vs baseline: 1.0414x; 1.0126x over previous
//
#include <hip/hip_runtime.h>
#include <hip/hip_bf16.h>

// Problem constants: B=2, S=2048, D=1024, H=16, HD=64
#define B_  2
#define S_  2048
#define D_  1024
#define H_  16
#define HD_ 64

using bf16x8  = __attribute__((ext_vector_type(8))) __bf16;
using floatx4 = __attribute__((ext_vector_type(4))) float;
using intx4   = __attribute__((ext_vector_type(4))) int;

__device__ __forceinline__ unsigned short f2bf(float f) {
  union { float f; unsigned int i; } v; v.f = f;
  unsigned int r = v.i + 0x7fffu + ((v.i >> 16) & 1u);   // RNE
  return (unsigned short)(r >> 16);
}
// packed f32x2 -> bf16x2 (v_cvt_pk_bf16_f32 on gfx950; header fallback = same RNE)
__device__ __forceinline__ unsigned int f2bf_pk(float a, float b) {
  union { __hip_bfloat162 h2; unsigned int u; } c;
  c.h2 = __float22bfloat162_rn(make_float2(a, b));
  return c.u;   // low 16 = a, high 16 = b
}
__device__ __forceinline__ floatx4 mfma16(bf16x8 a, bf16x8 b, floatx4 c) {
  return __builtin_amdgcn_mfma_f32_16x16x32_bf16(a, b, c, 0, 0, 0);
}
// async global->LDS, 16B/lane; LDS dest = wave-uniform base + lane*16
__device__ __forceinline__ void gld16(const unsigned short* g, unsigned short* l) {
  __builtin_amdgcn_global_load_lds(
      (const __attribute__((address_space(1))) unsigned int*)g,
      (__attribute__((address_space(3))) unsigned int*)l, 16, 0, 0);
}
// swizzles: ushort offset of 8-ushort group within a row
#define SW8(row, g) ((((g) ^ ((row) & 7)) * 8))          // 64-ushort rows
#define SW4(row, g) ((((g) ^ (((row) >> 1) & 3)) * 8))   // 32-ushort rows
// K-row permutation: LDS row r holds token TAU(r); bits (b5,b4,b3,b2,b1,b0) ->
// (b5,b3,b2,b4,b1,b0). Makes swapped-QK^T score layout == PV A-frag layout.
#define TAU(r) (((r) & 0x23) | (((r) & 0x08) << 1) | (((r) & 0x04) << 1) | (((r) & 0x10) >> 2))

// ---------------------------------------------------------------------------
// prep: one dispatch doing all pre-passes (launch-overhead fusion).
// blocks [0,2048): cvt x | [2048,3072): cvt w_in[0:2048] | [3072,3584): cvt
// w_out | [3584,5632): mask->bitpack | [5632,6656): V transpose to [B][H][HD][S]
// ---------------------------------------------------------------------------
__global__ __launch_bounds__(256) void prep_kernel(
    const float* __restrict__ x, const float* __restrict__ w_in,
    const float* __restrict__ w_out, const float* __restrict__ V,
    const float* __restrict__ Mm,
    unsigned short* __restrict__ xb, unsigned short* __restrict__ wb,
    unsigned short* __restrict__ wob, unsigned short* __restrict__ vt,
    unsigned long long* __restrict__ mpk)
{
  __shared__ unsigned short tile[64 * 72];
  const int bid = blockIdx.x, tid = threadIdx.x;

  if (bid < 3584) {                       // bulk fp32->bf16 converts
    const float* src; unsigned short* dst; int base;
    if (bid < 2048)      { src = x;     dst = xb;  base = bid; }
    else if (bid < 3072) { src = w_in;  dst = wb;  base = bid - 2048; }
    else                 { src = w_out; dst = wob; base = bid - 3072; }
    const int i = (base * 256 + tid) * 8;
    float4 a = *(const float4*)(src + i);
    float4 b = *(const float4*)(src + i + 4);
    union { unsigned int w[4]; intx4 v; } o;
    o.w[0] = f2bf_pk(a.x, a.y); o.w[1] = f2bf_pk(a.z, a.w);
    o.w[2] = f2bf_pk(b.x, b.y); o.w[3] = f2bf_pk(b.z, b.w);
    *(intx4*)(dst + i) = o.v;
  } else if (bid < 5632) {                // mask bit-pack, 64 words/block
    const int wave = tid >> 6, lane = tid & 63;
    const int w0 = (bid - 3584) * 64 + wave * 16;
#pragma unroll 4
    for (int j = 0; j < 16; ++j) {
      float v = Mm[(size_t)(w0 + j) * 64 + lane];
      unsigned long long bl = __ballot(v != 0.0f);
      if (lane == 0) mpk[w0 + j] = bl;
    }
  } else {                                 // V transpose (b,h,64-token tile)
    const int idx = bid - 5632;
    const int t0 = (idx & 31) * 64, h = (idx >> 5) & 15, b = idx >> 9;
    const int sr = tid >> 3, sc = (tid & 7) * 8;
    const float* src = V + ((size_t)((b * S_ + t0) * H_ + h)) * HD_;
#pragma unroll
    for (int half = 0; half < 2; ++half) {
      const int r = sr + half * 32;
      float4 v0 = *(const float4*)&src[(size_t)r * (H_ * HD_) + sc];
      float4 v1 = *(const float4*)&src[(size_t)r * (H_ * HD_) + sc + 4];
      union { unsigned int w[4]; intx4 v; } p;
      p.w[0] = f2bf_pk(v0.x, v0.y); p.w[1] = f2bf_pk(v0.z, v0.w);
      p.w[2] = f2bf_pk(v1.x, v1.y); p.w[3] = f2bf_pk(v1.z, v1.w);
      *(intx4*)&tile[r * 72 + sc] = p.v;
    }
    __syncthreads();
    unsigned short* dst = vt + ((size_t)((b * H_ + h) * HD_)) * S_ + t0;
    union { unsigned short u[8]; intx4 v; } pack;
#pragma unroll
    for (int j = 0; j < 8; ++j) pack.u[j] = tile[(sc + j) * 72 + sr];
    *(intx4*)&dst[(size_t)sr * S_ + sc] = pack.v;
#pragma unroll
    for (int j = 0; j < 8; ++j) pack.u[j] = tile[(sc + j) * 72 + sr + 32];
    *(intx4*)&dst[(size_t)(sr + 32) * S_ + sc] = pack.v;
  }
}

// ---------------------------------------------------------------------------
// bf16 MFMA GEMM (m97-style): C = A @ Bm^T + bias. 128x128, BK=32,
// global_load_lds + XOR-swizzled LDS. qscale: cols<1024 *= 0.125.
// ---------------------------------------------------------------------------
__global__ __launch_bounds__(256) void gemm_abt(
    const unsigned short* __restrict__ A,
    const unsigned short* __restrict__ Bm,
    const float* __restrict__ bias,
    unsigned short* __restrict__ Cb, float* __restrict__ Cf,
    int M, int N, int K, int qscale)
{
  __shared__ unsigned short As[128 * 32];
  __shared__ unsigned short Bs[128 * 32];

  const int tid  = threadIdx.x;
  const int wave = tid >> 6, lane = tid & 63;
  const int quad = lane >> 4, l15 = lane & 15;
  const int wr = wave >> 1, wc = wave & 1;
  const int bm = blockIdx.y * 128, bn = blockIdx.x * 128;
  const int srow = tid >> 2, gs = tid & 3;

  floatx4 acc[4][4];
#pragma unroll
  for (int mt = 0; mt < 4; ++mt)
#pragma unroll
    for (int nt = 0; nt < 4; ++nt)
      acc[mt][nt] = (floatx4){0.f, 0.f, 0.f, 0.f};

  for (int k0 = 0; k0 < K; k0 += 32) {
    __syncthreads();
#pragma unroll
    for (int r = 0; r < 2; ++r) {
      const int row = srow + r * 64;
      gld16(&A[(size_t)(bm + row) * K + k0 + SW4(row, gs)],
            &As[wave * 512 + r * 2048]);
      gld16(&Bm[(size_t)(bn + row) * K + k0 + SW4(row, gs)],
            &Bs[wave * 512 + r * 2048]);
    }
    __syncthreads();

    bf16x8 af[4], bf[4];
#pragma unroll
    for (int mt = 0; mt < 4; ++mt) {
      const int row = wr * 64 + mt * 16 + l15;
      af[mt] = *(const bf16x8*)&As[row * 32 + SW4(row, quad)];
    }
#pragma unroll
    for (int nt = 0; nt < 4; ++nt) {
      const int row = wc * 64 + nt * 16 + l15;
      bf[nt] = *(const bf16x8*)&Bs[row * 32 + SW4(row, quad)];
    }
#pragma unroll
    for (int mt = 0; mt < 4; ++mt)
#pragma unroll
      for (int nt = 0; nt < 4; ++nt)
        acc[mt][nt] = mfma16(af[mt], bf[nt], acc[mt][nt]);
  }

#pragma unroll
  for (int nt = 0; nt < 4; ++nt) {
    const int col = bn + wc * 64 + nt * 16 + l15;
    const float bi = bias[col];
    const float sc = (qscale && col < 1024) ? 0.125f : 1.0f;
#pragma unroll
    for (int mt = 0; mt < 4; ++mt) {
      const int row0 = bm + wr * 64 + mt * 16 + quad * 4;
#pragma unroll
      for (int reg = 0; reg < 4; ++reg) {
        const float v = (acc[mt][nt][reg] + bi) * sc;
        if (Cf) Cf[(size_t)(row0 + reg) * N + col] = v;
        else    Cb[(size_t)(row0 + reg) * N + col] = f2bf(v);
      }
    }
  }
}

// ---------------------------------------------------------------------------
// Fused masked-renorm attention: out = sum(e*M*V)/sum(e*M).
// R3: qb=64 per block (grid 1024 = 4 blocks/CU, 4 waves/SIMD) to attack the
// 20% occupancy. Wave owns 16 q-rows. Tile-level layout identical to R2:
// swapped QK^T + TAU-permuted K rows => P stays in registers (PV A-frag
// layout), no P LDS round-trip, mask via per-lane bit tests.
// ---------------------------------------------------------------------------
__global__ __launch_bounds__(256) void attn_kernel(
    const unsigned short* __restrict__ QK,      // [B*S][2048]
    const unsigned short* __restrict__ Vt,      // [B][H][HD][S]
    const unsigned long long* __restrict__ Mpk, // [B*S][S/64]
    unsigned short* __restrict__ ctx)           // [B*S][D]
{
  __shared__ unsigned short Ks[2][64 * 64];
  __shared__ unsigned short Vs[2][64 * 64];
  __shared__ unsigned long long Ms64[2][64];

  const int tid  = threadIdx.x;
  const int wave = tid >> 6, lane = tid & 63;
  const int quad = lane >> 4, l15 = lane & 15;
  const int b = blockIdx.z, h = blockIdx.y, qb = blockIdx.x * 64;
  const int gs = tid & 7;

  const unsigned short* Qbase = QK + (size_t)(b * S_ + qb) * 2048 + h * HD_;
  const unsigned short* Kbase = QK + (size_t)(b * S_) * 2048 + D_ + h * HD_;
  const unsigned short* Vbase = Vt + (size_t)((b * H_ + h) * HD_) * S_;
  const unsigned long long* Mbase = Mpk + (size_t)(b * S_ + qb) * (S_ / 64);

  // ---- stage Q (64x64, stride 64) into the Ks[0] region ----
  unsigned short* Qs = &Ks[0][0];
#pragma unroll
  for (int r = 0; r < 2; ++r) {
    const int row = (tid >> 3) + r * 32;
    gld16(Qbase + (size_t)row * 2048 + SW8(row, gs), Qs + wave * 512 + r * 2048);
  }
  if (tid < 64) Ms64[0][tid] = Mbase[(size_t)tid * (S_ / 64)];
  asm volatile("s_waitcnt vmcnt(0)" ::: "memory");
  __syncthreads();

  // loop-invariant Q fragments (rows wave*16..+15)
  bf16x8 qf[2];
#pragma unroll
  for (int c = 0; c < 2; ++c) {
    const int row = wave * 16 + l15;
    qf[c] = *(const bf16x8*)&Qs[row * 64 + SW8(row, c * 4 + quad)];
  }
  __syncthreads();   // all qf reads done before K tile-0 staging overwrites

  // ---- stage tile 0 K (TAU-permuted rows) and V ----
#pragma unroll
  for (int r = 0; r < 2; ++r) {
    const int rowd = (tid >> 3) + r * 32;
    const int tokK = TAU(rowd);
    gld16(Kbase + (size_t)tokK * 2048 + SW8(rowd, gs), &Ks[0][wave * 512 + r * 2048]);
    gld16(Vbase + (size_t)rowd * S_ + SW8(rowd, gs),   &Vs[0][wave * 512 + r * 2048]);
  }

  // per-lane mask bit-tests: token t = n1*32 + quad*8 + n0*4 + reg
  unsigned int bmask[8];
#pragma unroll
  for (int j = 0; j < 8; ++j) bmask[j] = 1u << (quad * 8 + j);

  floatx4 accO[4];
  float Pp = 0.f;
#pragma unroll
  for (int nt = 0; nt < 4; ++nt)
    accO[nt] = (floatx4){0.f, 0.f, 0.f, 0.f};

  for (int i = 0; i < 32; ++i) {
    const int cur = i & 1, nxt = cur ^ 1;
    asm volatile("s_waitcnt vmcnt(0)" ::: "memory");  // buf[cur] staged
    __syncthreads();  // all waves done with buf[nxt] (tile i-1)

    if (i + 1 < 32) {  // prefetch tile i+1
      const int t1 = (i + 1) * 64;
#pragma unroll
      for (int r = 0; r < 2; ++r) {
        const int rowd = (tid >> 3) + r * 32;
        const int tokK = TAU(rowd);
        gld16(Kbase + (size_t)(t1 + tokK) * 2048 + SW8(rowd, gs),
              &Ks[nxt][wave * 512 + r * 2048]);
        gld16(Vbase + (size_t)rowd * S_ + t1 + SW8(rowd, gs),
              &Vs[nxt][wave * 512 + r * 2048]);
      }
      if (tid < 64)
        Ms64[nxt][tid] = Mbase[(size_t)tid * (S_ / 64) + i + 1];
    }

    // S^T = K @ Q^T (swapped operands): lane l15 = q-row, quad/reg = token
    floatx4 sc[4];
    __builtin_amdgcn_s_setprio(1);
#pragma unroll
    for (int nt = 0; nt < 4; ++nt) {
      const int row = nt * 16 + l15;
      bf16x8 kf0 = *(const bf16x8*)&Ks[cur][row * 64 + SW8(row, quad)];
      bf16x8 kf1 = *(const bf16x8*)&Ks[cur][row * 64 + SW8(row, 4 + quad)];
      floatx4 z = (floatx4){0.f, 0.f, 0.f, 0.f};
      z = mfma16(kf0, qf[0], z);
      z = mfma16(kf1, qf[1], z);
      sc[nt] = z;
    }
    __builtin_amdgcn_s_setprio(0);

    // mask word: one 64-bit word per q-row (lane-local q = l15)
    const unsigned long long mw = Ms64[cur][wave * 16 + l15];

    // V fragments — independent of P, hoisted above the softmax
    bf16x8 vf0[4], vf1[4];
#pragma unroll
    for (int nt = 0; nt < 4; ++nt) {
      const int row = nt * 16 + l15;
      vf0[nt] = *(const bf16x8*)&Vs[cur][row * 64 + SW8(row, quad)];
      vf1[nt] = *(const bf16x8*)&Vs[cur][row * 64 + SW8(row, 4 + quad)];
    }

    // exp + mask + P-sum, pack straight into PV A-frags (in-register)
    bf16x8 pa0, pa1;
    {
      const unsigned int mlo = (unsigned int)mw;
      const unsigned int mhi = (unsigned int)(mw >> 32);
      union { unsigned int w[4]; bf16x8 v; } A0, A1;
#pragma unroll
      for (int nt = 0; nt < 4; ++nt) {
        const unsigned int word = (nt < 2) ? mlo : mhi;
        float p[4];
#pragma unroll
        for (int reg = 0; reg < 4; ++reg) {
          const float e = __expf(sc[nt][reg]);
          p[reg] = (word & bmask[(nt & 1) * 4 + reg]) ? e : 0.0f;
        }
        Pp += (p[0] + p[1]) + (p[2] + p[3]);
        const unsigned int d0 = f2bf_pk(p[0], p[1]);
        const unsigned int d1 = f2bf_pk(p[2], p[3]);
        if (nt == 0)      { A0.w[0] = d0; A0.w[1] = d1; }
        else if (nt == 1) { A0.w[2] = d0; A0.w[3] = d1; }
        else if (nt == 2) { A1.w[0] = d0; A1.w[1] = d1; }
        else              { A1.w[2] = d0; A1.w[3] = d1; }
      }
      pa0 = A0.v; pa1 = A1.v;
    }

    // O += P @ V^T (P already in A-frag layout)
    __builtin_amdgcn_s_setprio(1);
#pragma unroll
    for (int nt = 0; nt < 4; ++nt) {
      accO[nt] = mfma16(pa0, vf0[nt], accO[nt]);
      accO[nt] = mfma16(pa1, vf1[nt], accO[nt]);
    }
    __builtin_amdgcn_s_setprio(0);
  }

  // Pp: lane (quad,l15) holds partial row-sum for q-row l15 over that quad's
  // tokens. Reduce over quads (lane^16, lane^32).
  Pp += __shfl_xor(Pp, 16);
  Pp += __shfl_xor(Pp, 32);
  Pp = 1.0f / (Pp + 1e-30f);
  // redistribute: epilogue needs inv-sum for q-row quad*4 + reg
  float Ppe[4];
#pragma unroll
  for (int reg = 0; reg < 4; ++reg)
    Ppe[reg] = __shfl(Pp, (quad << 4) | (quad * 4 + reg));

#pragma unroll
  for (int nt = 0; nt < 4; ++nt)
#pragma unroll
    for (int reg = 0; reg < 4; ++reg) {
      const int row = wave * 16 + quad * 4 + reg;
      ctx[(size_t)(b * S_ + qb + row) * D_ + h * HD_ + nt * 16 + l15] =
          f2bf(accO[nt][reg] * Ppe[reg]);
    }
}

// ---------------------------------------------------------------------------
extern "C" void kernel_launch(void* const* d_in, const int* in_sizes, int n_in,
                              void* d_out, int out_size, void* d_ws, size_t ws_size,
                              hipStream_t stream) {
  const float* x     = (const float*)d_in[0];
  const float* V     = (const float*)d_in[1];
  const float* Mm    = (const float*)d_in[2];
  const float* w_in  = (const float*)d_in[3];
  const float* b_in  = (const float*)d_in[4];
  const float* w_out = (const float*)d_in[5];
  const float* b_out = (const float*)d_in[6];
  float* out = (float*)d_out;                  // fp32 (verified R5)

  // workspace layout (ushort units)
  unsigned short* qk  = (unsigned short*)d_ws;          // 8M   [4096][2048]
  unsigned short* vt  = qk  + (size_t)8 * 1024 * 1024;  // 4M   [B][H][HD][S]
  unsigned short* ctx = vt  + (size_t)4 * 1024 * 1024;  // 4M   [4096][1024]
  unsigned short* xb  = ctx + (size_t)4 * 1024 * 1024;  // 4M   bf16(x)
  unsigned short* wb  = xb  + (size_t)4 * 1024 * 1024;  // 2M   bf16(w_in[0:2048])
  unsigned short* wob = wb  + (size_t)2 * 1024 * 1024;  // 1M   bf16(out_w)
  unsigned long long* mpk = (unsigned long long*)(wob + (size_t)1024 * 1024);

  // 0) fused prep: converts + mask pack + V transpose (one dispatch)
  prep_kernel<<<6656, 256, 0, stream>>>(x, w_in, w_out, V, Mm,
                                        xb, wb, wob, vt, mpk);

  // 1) QK = x @ in_proj_w[0:2048]^T + b_in; Q cols pre-scaled by 0.125
  gemm_abt<<<dim3(2048 / 128, (B_ * S_) / 128), 256, 0, stream>>>(
      xb, wb, b_in, qk, nullptr, B_ * S_, 2048, D_, 1);

  // 2) fused masked-renorm attention -> ctx (bf16)
  attn_kernel<<<dim3(S_ / 64, H_, B_), 256, 0, stream>>>(qk, vt, mpk, ctx);

  // 3) out = ctx @ out_w^T + out_b  (fp32 store to d_out)
  gemm_abt<<<dim3(D_ / 128, (B_ * S_) / 128), 256, 0, stream>>>(
      ctx, wob, b_out, nullptr, out, B_ * S_, D_, D_, 0);
}